// Round 1
// 2225.796 us; speedup vs baseline: 1.5147x; 1.5147x over previous
//
#include <hip/hip_runtime.h>
#include <math.h>

#define B_  32
#define S_  512
#define H_  16
#define DH_ 64
#define DM_ 1024
#define T_  512

// sizes
#define NBHSD (B_*H_*S_*DH_)          // 16,777,216 elements (also B*S*DM)
#define OFF_ATTN ((size_t)B_*S_*DM_)  // mha_out element count in d_out

// ---------------------------------------------------------------------------
// Kernel 1: per-head Q/K/V projection.
//   out[b,h,s,e] = sum_d x[b,s,d] * W[h,e,d] + bias[h,e]
// grid (S/64, H, 3*B), block 256. 64s x 64e tile, K=64 in 2 chunks of 32.
// ---------------------------------------------------------------------------
__global__ __launch_bounds__(256)
void qkv_proj_kernel(const float* __restrict__ q_in, const float* __restrict__ k_in,
                     const float* __restrict__ v_in,
                     const float* __restrict__ Wq, const float* __restrict__ bq,
                     const float* __restrict__ Wk, const float* __restrict__ bk,
                     const float* __restrict__ Wv, const float* __restrict__ bv,
                     float* __restrict__ Qo, float* __restrict__ Ko, float* __restrict__ Vo)
{
    const int stile = blockIdx.x;        // 8 tiles of 64 s-rows
    const int h     = blockIdx.y;
    const int which = blockIdx.z / B_;   // 0=q,1=k,2=v
    const int b     = blockIdx.z % B_;

    const float* xin; const float* W; const float* bias; float* out;
    if (which == 0)      { xin = q_in; W = Wq; bias = bq; out = Qo; }
    else if (which == 1) { xin = k_in; W = Wk; bias = bk; out = Ko; }
    else                 { xin = v_in; W = Wv; bias = bv; out = Vo; }

    __shared__ float sA[32*68];   // [d][s]  X^T chunk
    __shared__ float sW[32*68];   // [d][e]  W^T chunk

    const int tid = threadIdx.x;
    const int dg = tid & 15;      // e quad: e = dg*4 + j
    const int tg = tid >> 4;      // s quad: s = tg*4 + i  (within tile)
    const int s0 = stile * 64;

    float acc[4][4];
    #pragma unroll
    for (int i=0;i<4;i++)
        #pragma unroll
        for (int j=0;j<4;j++) acc[i][j]=0.f;

    for (int dc = 0; dc < 64; dc += 32) {
        __syncthreads();
        // load X rows [64 s][32 d] -> sA[d][s]
        for (int idx = tid; idx < 64*32; idx += 256) {
            int s = idx >> 5, d = idx & 31;
            sA[d*68 + s] = xin[((size_t)b*S_ + s0 + s)*DH_ + dc + d];
        }
        // load W [64 e][32 d] -> sW[d][e]
        for (int idx = tid; idx < 64*32; idx += 256) {
            int e = idx >> 5, d = idx & 31;
            sW[d*68 + e] = W[(size_t)h*DH_*DH_ + (size_t)e*DH_ + dc + d];
        }
        __syncthreads();
        #pragma unroll
        for (int kk = 0; kk < 32; kk++) {
            const float4 a4 = *(const float4*)&sA[kk*68 + tg*4];
            const float4 w4 = *(const float4*)&sW[kk*68 + dg*4];
            const float a[4] = {a4.x,a4.y,a4.z,a4.w};
            const float w[4] = {w4.x,w4.y,w4.z,w4.w};
            #pragma unroll
            for (int i=0;i<4;i++)
                #pragma unroll
                for (int j=0;j<4;j++)
                    acc[i][j] = fmaf(a[i], w[j], acc[i][j]);
        }
    }

    // store with bias along e (columns)
    const float4 bv4 = *(const float4*)&bias[h*DH_ + dg*4];
    const float bb[4] = {bv4.x,bv4.y,bv4.z,bv4.w};
    #pragma unroll
    for (int i=0;i<4;i++) {
        int s = s0 + tg*4 + i;
        float4 o;
        o.x = acc[i][0]+bb[0]; o.y = acc[i][1]+bb[1];
        o.z = acc[i][2]+bb[2]; o.w = acc[i][3]+bb[3];
        *(float4*)&out[(((size_t)b*H_ + h)*S_ + s)*DH_ + dg*4] = o;
    }
}

// ---------------------------------------------------------------------------
// Kernel 2/4 (shared): Y[bh][m][d] = sum_k A[m][k] * X[bh][k][d]  (+bias[m])
//   128 m-rows x 64 d-cols per block, K-chunks of 32. 256 threads, 4x8/thread.
//   Per kk: 1 bcast float4 (A) + 2 float4 (X) = 48B for 32 FMA -> VALU-bound.
//   Output addressing: Y[(bh>>4)*y_b_stride + (bh&15)*y_h_stride
//                        + (mtile*128+m)*y_row_stride + d]
// grid (M/128, B*H), block 256.
// ---------------------------------------------------------------------------
__global__ __launch_bounds__(256)
void gemm128x64_kernel(const float* __restrict__ A, long a_bh_stride, int K,
                       const float* __restrict__ X, long x_bh_stride,
                       const float* __restrict__ bias,
                       float* __restrict__ Y, long y_b_stride, long y_h_stride,
                       int y_row_stride)
{
    const int mtile = blockIdx.x;
    const int bh    = blockIdx.y;

    const float* Ab = A + (long)bh * a_bh_stride + (long)mtile*128*K;
    const float* Xb = X + (long)bh * x_bh_stride;

    __shared__ float sA[32*132];  // [k][m]  (transposed A tile) 16.9 KB
    __shared__ float sX[32*72];   // [k][d]                        9.2 KB

    const int tid = threadIdx.x;
    const int mg = tid >> 3;      // 0..31 : m = mg*4 + i
    const int dg = tid & 7;       // 0..7  : d = dg*8 + j

    float acc[4][8];
    #pragma unroll
    for (int i=0;i<4;i++)
        #pragma unroll
        for (int j=0;j<8;j++) acc[i][j]=0.f;

    for (int kc = 0; kc < K; kc += 32) {
        __syncthreads();
        // A tile [128 m][32 k] -> sA[k][m] (transposed store)
        #pragma unroll
        for (int w = 0; w < 4; w++) {
            int idx = tid + w*256;            // 0..1023
            int m = idx >> 3, k4 = idx & 7;
            float4 v = *(const float4*)&Ab[(long)m*K + kc + k4*4];
            sA[(k4*4+0)*132 + m] = v.x;
            sA[(k4*4+1)*132 + m] = v.y;
            sA[(k4*4+2)*132 + m] = v.z;
            sA[(k4*4+3)*132 + m] = v.w;
        }
        // X tile [32 k][64 d] -> sX[k][d] (direct, contiguous region)
        #pragma unroll
        for (int w = 0; w < 2; w++) {
            int idx = tid + w*256;            // 0..511
            int k = idx >> 4, d4 = idx & 15;
            *(float4*)&sX[k*72 + d4*4] = *(const float4*)&Xb[(long)(kc+k)*64 + d4*4];
        }
        __syncthreads();
        #pragma unroll
        for (int kk = 0; kk < 32; kk++) {
            const float4 a4 = *(const float4*)&sA[kk*132 + mg*4];
            const float4 x0 = *(const float4*)&sX[kk*72 + dg*8];
            const float4 x1 = *(const float4*)&sX[kk*72 + dg*8 + 4];
            const float a[4] = {a4.x,a4.y,a4.z,a4.w};
            const float x[8] = {x0.x,x0.y,x0.z,x0.w,x1.x,x1.y,x1.z,x1.w};
            #pragma unroll
            for (int i=0;i<4;i++)
                #pragma unroll
                for (int j=0;j<8;j++)
                    acc[i][j] = fmaf(a[i], x[j], acc[i][j]);
        }
    }

    const long ybase = (long)(bh >> 4)*y_b_stride + (long)(bh & 15)*y_h_stride
                     + (long)mtile*128*y_row_stride;
    #pragma unroll
    for (int i=0;i<4;i++) {
        int m = mg*4 + i;
        float bval = bias ? bias[mtile*128 + m] : 0.f;
        float4 o0, o1;
        o0.x = acc[i][0]+bval; o0.y = acc[i][1]+bval;
        o0.z = acc[i][2]+bval; o0.w = acc[i][3]+bval;
        o1.x = acc[i][4]+bval; o1.y = acc[i][5]+bval;
        o1.z = acc[i][6]+bval; o1.w = acc[i][7]+bval;
        *(float4*)&Y[ybase + (long)m*y_row_stride + dg*8]     = o0;
        *(float4*)&Y[ybase + (long)m*y_row_stride + dg*8 + 4] = o1;
    }
}

// ---------------------------------------------------------------------------
// Kernel 3: scores + softmax, register-resident scores.
//   32 s-rows per block; t in 4 chunks of 128; 4x4 per thread per chunk.
//   Q and KEt staged TRANSPOSED ([d][s], [d][t]) so each kk needs
//   1 broadcast float4 (Q, free bank-wise) + 1 float4 (K) for 16 FMA.
//   Scale 0.125 folded into the Q LDS store.
// grid (S/32, B*H), block 256.
// ---------------------------------------------------------------------------
__global__ __launch_bounds__(256)
void attn_softmax_kernel(const float* __restrict__ Q, const float* __restrict__ KEt,
                         float* __restrict__ attnOut)
{
    const int stile = blockIdx.x;   // 16 tiles of 32 rows
    const int bh    = blockIdx.y;

    __shared__ float sQt[64*36];    // [d][s]  9.2 KB
    __shared__ float sKt[64*132];   // [d][t-chunk of 128] 33.8 KB

    const int tid = threadIdx.x;
    const int sq  = tid >> 5;       // 0..7 : rows r = sq*4 + i
    const int tq  = tid & 31;       // 0..31: t = c*128 + tq*4 + j
    const int s0  = stile * 32;

    // load Q tile [32 s][64 d] -> sQt[d][s], pre-scaled by 1/8
    #pragma unroll
    for (int w = 0; w < 2; w++) {
        int idx = tid + w*256;      // 0..511
        int s = idx >> 4, d4 = idx & 15;
        float4 v = *(const float4*)&Q[((size_t)bh*S_ + s0 + s)*DH_ + d4*4];
        sQt[(d4*4+0)*36 + s] = v.x * 0.125f;
        sQt[(d4*4+1)*36 + s] = v.y * 0.125f;
        sQt[(d4*4+2)*36 + s] = v.z * 0.125f;
        sQt[(d4*4+3)*36 + s] = v.w * 0.125f;
    }

    float p[4][4][4];               // [chunk][row i][t j] - all static indexing

    #pragma unroll
    for (int c = 0; c < 4; c++) {
        __syncthreads();            // protects sKt reuse (and sQt on c==0)
        // load KEt chunk [128 t][64 d] -> sKt[d][t]
        #pragma unroll
        for (int w = 0; w < 8; w++) {
            int idx = tid + w*256;  // 0..2047
            int t = idx >> 4, d4 = idx & 15;
            float4 v = *(const float4*)&KEt[((size_t)bh*T_ + c*128 + t)*DH_ + d4*4];
            sKt[(d4*4+0)*132 + t] = v.x;
            sKt[(d4*4+1)*132 + t] = v.y;
            sKt[(d4*4+2)*132 + t] = v.z;
            sKt[(d4*4+3)*132 + t] = v.w;
        }
        __syncthreads();

        #pragma unroll
        for (int i=0;i<4;i++)
            #pragma unroll
            for (int j=0;j<4;j++) p[c][i][j] = 0.f;

        #pragma unroll
        for (int kk = 0; kk < 64; kk++) {
            const float4 q4 = *(const float4*)&sQt[kk*36 + sq*4];   // bcast x32
            const float4 k4 = *(const float4*)&sKt[kk*132 + tq*4];
            const float q[4] = {q4.x,q4.y,q4.z,q4.w};
            const float k[4] = {k4.x,k4.y,k4.z,k4.w};
            #pragma unroll
            for (int i=0;i<4;i++)
                #pragma unroll
                for (int j=0;j<4;j++)
                    p[c][i][j] = fmaf(q[i], k[j], p[c][i][j]);
        }
    }

    // softmax over t (16 in-thread values x 32 lanes) per row i
    #pragma unroll
    for (int i = 0; i < 4; i++) {
        float m = -INFINITY;
        #pragma unroll
        for (int c = 0; c < 4; c++)
            #pragma unroll
            for (int j = 0; j < 4; j++) m = fmaxf(m, p[c][i][j]);
        #pragma unroll
        for (int off = 16; off >= 1; off >>= 1) m = fmaxf(m, __shfl_xor(m, off));

        float sum = 0.f;
        #pragma unroll
        for (int c = 0; c < 4; c++)
            #pragma unroll
            for (int j = 0; j < 4; j++) {
                p[c][i][j] = __expf(p[c][i][j] - m);
                sum += p[c][i][j];
            }
        #pragma unroll
        for (int off = 16; off >= 1; off >>= 1) sum += __shfl_xor(sum, off);
        const float inv = 1.f / sum;

        const size_t rowbase = ((size_t)bh*S_ + s0 + sq*4 + i)*T_;
        #pragma unroll
        for (int c = 0; c < 4; c++) {
            float4 o;
            o.x = p[c][i][0]*inv; o.y = p[c][i][1]*inv;
            o.z = p[c][i][2]*inv; o.w = p[c][i][3]*inv;
            *(float4*)&attnOut[rowbase + c*128 + tq*4] = o;
        }
    }
}

// ---------------------------------------------------------------------------
// Kernel 5: out projection. C[i][n] = sum_k MHA[i][k]*Wout[n][k] + bout[n]
//   128x128 tile, 8x8 per thread, K-chunks of 32.
// grid (B*S/128, DM/128), block 256.
// ---------------------------------------------------------------------------
__global__ __launch_bounds__(256)
void outproj_kernel(const float* __restrict__ MHA, const float* __restrict__ Wout,
                    const float* __restrict__ bout, float* __restrict__ Yout)
{
    const int i0 = blockIdx.x*128;
    const int n0 = blockIdx.y*128;

    __shared__ float sA[32*132];   // [k][i] 16.9 KB
    __shared__ float sW[32*132];   // [k][n] 16.9 KB

    const int tid = threadIdx.x;
    const int mg = tid >> 4;      // 0..15 : i = i0 + mg*8 + ii
    const int ng = tid & 15;      // 0..15 : n = n0 + ng*8 + j

    float acc[8][8];
    #pragma unroll
    for (int i=0;i<8;i++)
        #pragma unroll
        for (int j=0;j<8;j++) acc[i][j]=0.f;

    for (int kc = 0; kc < DM_; kc += 32) {
        __syncthreads();
        #pragma unroll
        for (int w = 0; w < 4; w++) {
            int idx = tid + w*256;            // 0..1023
            int m = idx >> 3, k4 = idx & 7;
            float4 v = *(const float4*)&MHA[(long)(i0 + m)*DM_ + kc + k4*4];
            sA[(k4*4+0)*132 + m] = v.x;
            sA[(k4*4+1)*132 + m] = v.y;
            sA[(k4*4+2)*132 + m] = v.z;
            sA[(k4*4+3)*132 + m] = v.w;
        }
        #pragma unroll
        for (int w = 0; w < 4; w++) {
            int idx = tid + w*256;
            int n = idx >> 3, k4 = idx & 7;
            float4 v = *(const float4*)&Wout[(long)(n0 + n)*DM_ + kc + k4*4];
            sW[(k4*4+0)*132 + n] = v.x;
            sW[(k4*4+1)*132 + n] = v.y;
            sW[(k4*4+2)*132 + n] = v.z;
            sW[(k4*4+3)*132 + n] = v.w;
        }
        __syncthreads();
        #pragma unroll
        for (int kk = 0; kk < 32; kk++) {
            const float4 a0 = *(const float4*)&sA[kk*132 + mg*8];
            const float4 a1 = *(const float4*)&sA[kk*132 + mg*8 + 4];
            const float4 b0 = *(const float4*)&sW[kk*132 + ng*8];
            const float4 b1 = *(const float4*)&sW[kk*132 + ng*8 + 4];
            const float a[8] = {a0.x,a0.y,a0.z,a0.w,a1.x,a1.y,a1.z,a1.w};
            const float b[8] = {b0.x,b0.y,b0.z,b0.w,b1.x,b1.y,b1.z,b1.w};
            #pragma unroll
            for (int i=0;i<8;i++)
                #pragma unroll
                for (int j=0;j<8;j++)
                    acc[i][j] = fmaf(a[i], b[j], acc[i][j]);
        }
    }

    const float4 bv0 = *(const float4*)&bout[n0 + ng*8];
    const float4 bv1 = *(const float4*)&bout[n0 + ng*8 + 4];
    const float bb[8] = {bv0.x,bv0.y,bv0.z,bv0.w,bv1.x,bv1.y,bv1.z,bv1.w};
    #pragma unroll
    for (int i=0;i<8;i++) {
        const long row = (long)(i0 + mg*8 + i)*DM_ + n0 + ng*8;
        float4 o0, o1;
        o0.x = acc[i][0]+bb[0]; o0.y = acc[i][1]+bb[1];
        o0.z = acc[i][2]+bb[2]; o0.w = acc[i][3]+bb[3];
        o1.x = acc[i][4]+bb[4]; o1.y = acc[i][5]+bb[5];
        o1.z = acc[i][6]+bb[6]; o1.w = acc[i][7]+bb[7];
        *(float4*)&Yout[row]     = o0;
        *(float4*)&Yout[row + 4] = o1;
    }
}

// ---------------------------------------------------------------------------
extern "C" void kernel_launch(void* const* d_in, const int* in_sizes, int n_in,
                              void* d_out, int out_size, void* d_ws, size_t ws_size,
                              hipStream_t stream)
{
    const float* query = (const float*)d_in[0];
    const float* key   = (const float*)d_in[1];
    const float* value = (const float*)d_in[2];
    const float* Wq    = (const float*)d_in[3];
    const float* bq    = (const float*)d_in[4];
    const float* Wk    = (const float*)d_in[5];
    const float* bk    = (const float*)d_in[6];
    const float* Wv    = (const float*)d_in[7];
    const float* bv    = (const float*)d_in[8];
    const float* E_w   = (const float*)d_in[9];
    const float* E_b   = (const float*)d_in[10];
    const float* F_w   = (const float*)d_in[11];
    const float* F_b   = (const float*)d_in[12];
    const float* out_w = (const float*)d_in[13];
    const float* out_b = (const float*)d_in[14];

    float* ws   = (float*)d_ws;
    float* Qb   = ws;                    // [B,H,S,DH]
    float* Kb   = ws + (size_t)NBHSD;    // [B,H,S,DH]
    float* Vb   = ws + (size_t)2*NBHSD;  // [B,H,S,DH]
    float* KEt  = ws + (size_t)3*NBHSD;  // [B,H,T,DH]
    float* VF   = ws + (size_t)4*NBHSD;  // [B,H,T,DH]
    float* MHA  = Qb;                    // reuse Q slot after attn kernel: [B,S,DM]

    float* mha_out = (float*)d_out;                 // [B,S,DM]
    float* attn    = (float*)d_out + OFF_ATTN;      // [B,H,S,T]

    // 1) Q/K/V projections
    qkv_proj_kernel<<<dim3(S_/64, H_, 3*B_), 256, 0, stream>>>(
        query, key, value, Wq, bq, Wk, bk, Wv, bv, Qb, Kb, Vb);

    // 2) KEt[bh][t][d] = sum_s E_w[t,s]*K[bh,s,d] + E_b[t]
    gemm128x64_kernel<<<dim3(T_/128, B_*H_), 256, 0, stream>>>(
        E_w, 0, S_, Kb, (long)S_*DH_, E_b,
        KEt, (long)H_*T_*DH_, (long)T_*DH_, DH_);
    //    VF[bh][t][d] = sum_s F_w[t,s]*V[bh,s,d] + F_b[t]
    gemm128x64_kernel<<<dim3(T_/128, B_*H_), 256, 0, stream>>>(
        F_w, 0, S_, Vb, (long)S_*DH_, F_b,
        VF, (long)H_*T_*DH_, (long)T_*DH_, DH_);

    // 3) attn = softmax(Q . KEt^T / 8) -> d_out attn region
    attn_softmax_kernel<<<dim3(S_/32, B_*H_), 256, 0, stream>>>(Qb, KEt, attn);

    // 4) head_out -> MHA[b][s][h*64+d] = sum_t attn[bh,s,t]*VF[bh,t,d]
    gemm128x64_kernel<<<dim3(S_/128, B_*H_), 256, 0, stream>>>(
        attn, (long)S_*T_, T_, VF, (long)T_*DH_, nullptr,
        MHA, (long)S_*DM_, (long)DH_, DM_);

    // 5) output projection
    outproj_kernel<<<dim3(B_*S_/128, DM_/128), 256, 0, stream>>>(
        MHA, out_w, out_b, mha_out);
}

// Round 2
// 2113.844 us; speedup vs baseline: 1.5949x; 1.0530x over previous
//
#include <hip/hip_runtime.h>
#include <math.h>

#define B_  32
#define S_  512
#define H_  16
#define DH_ 64
#define DM_ 1024
#define T_  512

// sizes
#define NBHSD (B_*H_*S_*DH_)          // 16,777,216 elements (also B*S*DM)
#define OFF_ATTN ((size_t)B_*S_*DM_)  // mha_out element count in d_out

// ---------------------------------------------------------------------------
// Kernel 1: per-head Q/K/V projection.  (unchanged this round)
//   out[b,h,s,e] = sum_d x[b,s,d] * W[h,e,d] + bias[h,e]
// grid (S/64, H, 3*B), block 256.
// ---------------------------------------------------------------------------
__global__ __launch_bounds__(256)
void qkv_proj_kernel(const float* __restrict__ q_in, const float* __restrict__ k_in,
                     const float* __restrict__ v_in,
                     const float* __restrict__ Wq, const float* __restrict__ bq,
                     const float* __restrict__ Wk, const float* __restrict__ bk,
                     const float* __restrict__ Wv, const float* __restrict__ bv,
                     float* __restrict__ Qo, float* __restrict__ Ko, float* __restrict__ Vo)
{
    const int stile = blockIdx.x;        // 8 tiles of 64 s-rows
    const int h     = blockIdx.y;
    const int which = blockIdx.z / B_;   // 0=q,1=k,2=v
    const int b     = blockIdx.z % B_;

    const float* xin; const float* W; const float* bias; float* out;
    if (which == 0)      { xin = q_in; W = Wq; bias = bq; out = Qo; }
    else if (which == 1) { xin = k_in; W = Wk; bias = bk; out = Ko; }
    else                 { xin = v_in; W = Wv; bias = bv; out = Vo; }

    __shared__ float sA[32*68];   // [d][s]  X^T chunk
    __shared__ float sW[32*68];   // [d][e]  W^T chunk

    const int tid = threadIdx.x;
    const int dg = tid & 15;      // e quad: e = dg*4 + j
    const int tg = tid >> 4;      // s quad: s = tg*4 + i  (within tile)
    const int s0 = stile * 64;

    float acc[4][4];
    #pragma unroll
    for (int i=0;i<4;i++)
        #pragma unroll
        for (int j=0;j<4;j++) acc[i][j]=0.f;

    for (int dc = 0; dc < 64; dc += 32) {
        __syncthreads();
        for (int idx = tid; idx < 64*32; idx += 256) {
            int s = idx >> 5, d = idx & 31;
            sA[d*68 + s] = xin[((size_t)b*S_ + s0 + s)*DH_ + dc + d];
        }
        for (int idx = tid; idx < 64*32; idx += 256) {
            int e = idx >> 5, d = idx & 31;
            sW[d*68 + e] = W[(size_t)h*DH_*DH_ + (size_t)e*DH_ + dc + d];
        }
        __syncthreads();
        #pragma unroll
        for (int kk = 0; kk < 32; kk++) {
            const float4 a4 = *(const float4*)&sA[kk*68 + tg*4];
            const float4 w4 = *(const float4*)&sW[kk*68 + dg*4];
            const float a[4] = {a4.x,a4.y,a4.z,a4.w};
            const float w[4] = {w4.x,w4.y,w4.z,w4.w};
            #pragma unroll
            for (int i=0;i<4;i++)
                #pragma unroll
                for (int j=0;j<4;j++)
                    acc[i][j] = fmaf(a[i], w[j], acc[i][j]);
        }
    }

    const float4 bv4 = *(const float4*)&bias[h*DH_ + dg*4];
    const float bb[4] = {bv4.x,bv4.y,bv4.z,bv4.w};
    #pragma unroll
    for (int i=0;i<4;i++) {
        int s = s0 + tg*4 + i;
        float4 o;
        o.x = acc[i][0]+bb[0]; o.y = acc[i][1]+bb[1];
        o.z = acc[i][2]+bb[2]; o.w = acc[i][3]+bb[3];
        *(float4*)&out[(((size_t)b*H_ + h)*S_ + s)*DH_ + dg*4] = o;
    }
}

// ---------------------------------------------------------------------------
// Kernel 2/4 (shared): Y[bh][m][d] = sum_k A[m][k] * X[bh][k][d]  (+bias[m])
//   128 m-rows x 64 d-cols per block, K-chunks of 32. 256 threads, 4x8/thread.
//   sA XOR-swizzled (col-group ^ (row>>2)) -> conflict-free transposed stores;
//   d-blocking split dg*4 / 32+dg*4 -> contiguous broadcast reads.
// grid (M/128, B*H), block 256.
// ---------------------------------------------------------------------------
__global__ __launch_bounds__(256)
void gemm128x64_kernel(const float* __restrict__ A, long a_bh_stride, int K,
                       const float* __restrict__ X, long x_bh_stride,
                       const float* __restrict__ bias,
                       float* __restrict__ Y, long y_b_stride, long y_h_stride,
                       int y_row_stride)
{
    const int mtile = blockIdx.x;
    const int bh    = blockIdx.y;

    const float* Ab = A + (long)bh * a_bh_stride + (long)mtile*128*K;
    const float* Xb = X + (long)bh * x_bh_stride;

    __shared__ float sA[32*132];  // [k][m swizzled] 16.9 KB
    __shared__ float sX[32*72];   // [k][d]           9.2 KB

    const int tid = threadIdx.x;
    const int mg = tid >> 3;      // 0..31 : m = mg*4 + i
    const int dg = tid & 7;       // 0..7  : d = dg*4 + j  and  32 + dg*4 + j
    const int mg4 = mg << 2;
    const int dg4 = dg << 2;

    float acc[4][8];
    #pragma unroll
    for (int i=0;i<4;i++)
        #pragma unroll
        for (int j=0;j<8;j++) acc[i][j]=0.f;

    for (int kc = 0; kc < K; kc += 32) {
        __syncthreads();
        // A tile [128 m][32 k] -> sA[k][m-swizzled] (transposed store)
        #pragma unroll
        for (int w = 0; w < 4; w++) {
            int idx = tid + w*256;            // 0..1023
            int m = idx >> 3, k4 = idx & 7;
            float4 v = *(const float4*)&Ab[(long)m*K + kc + k4*4];
            int col = (((m >> 2) ^ k4) << 2) + (m & 3);   // swizzled column
            sA[(k4*4+0)*132 + col] = v.x;
            sA[(k4*4+1)*132 + col] = v.y;
            sA[(k4*4+2)*132 + col] = v.z;
            sA[(k4*4+3)*132 + col] = v.w;
        }
        // X tile [32 k][64 d] -> sX[k][d] (direct, no swizzle needed)
        #pragma unroll
        for (int w = 0; w < 2; w++) {
            int idx = tid + w*256;            // 0..511
            int k = idx >> 4, d4 = idx & 15;
            *(float4*)&sX[k*72 + d4*4] = *(const float4*)&Xb[(long)(kc+k)*64 + d4*4];
        }
        __syncthreads();
        #pragma unroll
        for (int kk = 0; kk < 32; kk++) {
            const int sm = mg4 ^ ((kk >> 2) << 2);        // swizzled read col
            const float4 a4 = *(const float4*)&sA[kk*132 + sm];
            const float4 x0 = *(const float4*)&sX[kk*72 + dg4];
            const float4 x1 = *(const float4*)&sX[kk*72 + 32 + dg4];
            const float a[4] = {a4.x,a4.y,a4.z,a4.w};
            const float x[8] = {x0.x,x0.y,x0.z,x0.w,x1.x,x1.y,x1.z,x1.w};
            #pragma unroll
            for (int i=0;i<4;i++)
                #pragma unroll
                for (int j=0;j<8;j++)
                    acc[i][j] = fmaf(a[i], x[j], acc[i][j]);
        }
    }

    const long ybase = (long)(bh >> 4)*y_b_stride + (long)(bh & 15)*y_h_stride
                     + (long)mtile*128*y_row_stride;
    #pragma unroll
    for (int i=0;i<4;i++) {
        int m = mg4 + i;
        float bval = bias ? bias[mtile*128 + m] : 0.f;
        float4 o0, o1;
        o0.x = acc[i][0]+bval; o0.y = acc[i][1]+bval;
        o0.z = acc[i][2]+bval; o0.w = acc[i][3]+bval;
        o1.x = acc[i][4]+bval; o1.y = acc[i][5]+bval;
        o1.z = acc[i][6]+bval; o1.w = acc[i][7]+bval;
        *(float4*)&Y[ybase + (long)m*y_row_stride + dg4]      = o0;   // d = dg*4..
        *(float4*)&Y[ybase + (long)m*y_row_stride + 32 + dg4] = o1;   // d = 32+dg*4..
    }
}

// ---------------------------------------------------------------------------
// Kernel 3: scores + softmax, register-resident scores.
//   32 s-rows per block; t in 4 chunks of 128; 4x4 per thread per chunk.
//   sKt XOR-swizzled: store col-group (t>>2)^d4, read group tq^(kk>>2).
// grid (S/32, B*H), block 256.
// ---------------------------------------------------------------------------
__global__ __launch_bounds__(256)
void attn_softmax_kernel(const float* __restrict__ Q, const float* __restrict__ KEt,
                         float* __restrict__ attnOut)
{
    const int stile = blockIdx.x;   // 16 tiles of 32 rows
    const int bh    = blockIdx.y;

    __shared__ float sQt[64*36];    // [d][s]  9.2 KB
    __shared__ float sKt[64*132];   // [d][t-chunk swizzled] 33.8 KB

    const int tid = threadIdx.x;
    const int sq  = tid >> 5;       // 0..7 : rows r = sq*4 + i
    const int tq  = tid & 31;       // 0..31: t = c*128 + tq*4 + j
    const int tq4 = tq << 2;
    const int s0  = stile * 32;

    // load Q tile [32 s][64 d] -> sQt[d][s], pre-scaled by 1/8
    #pragma unroll
    for (int w = 0; w < 2; w++) {
        int idx = tid + w*256;      // 0..511
        int s = idx >> 4, d4 = idx & 15;
        float4 v = *(const float4*)&Q[((size_t)bh*S_ + s0 + s)*DH_ + d4*4];
        sQt[(d4*4+0)*36 + s] = v.x * 0.125f;
        sQt[(d4*4+1)*36 + s] = v.y * 0.125f;
        sQt[(d4*4+2)*36 + s] = v.z * 0.125f;
        sQt[(d4*4+3)*36 + s] = v.w * 0.125f;
    }

    float p[4][4][4];               // [chunk][row i][t j] - all static indexing

    #pragma unroll
    for (int c = 0; c < 4; c++) {
        __syncthreads();            // protects sKt reuse (and sQt on c==0)
        // load KEt chunk [128 t][64 d] -> sKt[d][t-swizzled]
        #pragma unroll
        for (int w = 0; w < 8; w++) {
            int idx = tid + w*256;  // 0..2047
            int t = idx >> 4, d4 = idx & 15;
            float4 v = *(const float4*)&KEt[((size_t)bh*T_ + c*128 + t)*DH_ + d4*4];
            int col = (((t >> 2) ^ d4) << 2) + (t & 3);   // swizzled column
            sKt[(d4*4+0)*132 + col] = v.x;
            sKt[(d4*4+1)*132 + col] = v.y;
            sKt[(d4*4+2)*132 + col] = v.z;
            sKt[(d4*4+3)*132 + col] = v.w;
        }
        __syncthreads();

        #pragma unroll
        for (int i=0;i<4;i++)
            #pragma unroll
            for (int j=0;j<4;j++) p[c][i][j] = 0.f;

        #pragma unroll
        for (int kk = 0; kk < 64; kk++) {
            const float4 q4 = *(const float4*)&sQt[kk*36 + sq*4];   // bcast x32
            const int st = tq4 ^ ((kk >> 2) << 2);                  // swizzled col
            const float4 k4 = *(const float4*)&sKt[kk*132 + st];
            const float q[4] = {q4.x,q4.y,q4.z,q4.w};
            const float k[4] = {k4.x,k4.y,k4.z,k4.w};
            #pragma unroll
            for (int i=0;i<4;i++)
                #pragma unroll
                for (int j=0;j<4;j++)
                    p[c][i][j] = fmaf(q[i], k[j], p[c][i][j]);
        }
    }

    // softmax over t (16 in-thread values x 32 lanes) per row i
    #pragma unroll
    for (int i = 0; i < 4; i++) {
        float m = -INFINITY;
        #pragma unroll
        for (int c = 0; c < 4; c++)
            #pragma unroll
            for (int j = 0; j < 4; j++) m = fmaxf(m, p[c][i][j]);
        #pragma unroll
        for (int off = 16; off >= 1; off >>= 1) m = fmaxf(m, __shfl_xor(m, off));

        float sum = 0.f;
        #pragma unroll
        for (int c = 0; c < 4; c++)
            #pragma unroll
            for (int j = 0; j < 4; j++) {
                p[c][i][j] = __expf(p[c][i][j] - m);
                sum += p[c][i][j];
            }
        #pragma unroll
        for (int off = 16; off >= 1; off >>= 1) sum += __shfl_xor(sum, off);
        const float inv = 1.f / sum;

        const size_t rowbase = ((size_t)bh*S_ + s0 + sq*4 + i)*T_;
        #pragma unroll
        for (int c = 0; c < 4; c++) {
            float4 o;
            o.x = p[c][i][0]*inv; o.y = p[c][i][1]*inv;
            o.z = p[c][i][2]*inv; o.w = p[c][i][3]*inv;
            *(float4*)&attnOut[rowbase + c*128 + tq4] = o;
        }
    }
}

// ---------------------------------------------------------------------------
// Kernel 5: out projection. C[i][n] = sum_k MHA[i][k]*Wout[n][k] + bout[n]
//   128x128 tile, 8x8 per thread as 2x(4) x 2x(4) halves at +-64
//   (contiguous conflict-free reads), sA/sW XOR-swizzled transposed stores.
// grid (B*S/128, DM/128), block 256.
// ---------------------------------------------------------------------------
__global__ __launch_bounds__(256)
void outproj_kernel(const float* __restrict__ MHA, const float* __restrict__ Wout,
                    const float* __restrict__ bout, float* __restrict__ Yout)
{
    const int i0 = blockIdx.x*128;
    const int n0 = blockIdx.y*128;

    __shared__ float sA[32*132];   // [k][i swizzled] 16.9 KB
    __shared__ float sW[32*132];   // [k][n swizzled] 16.9 KB

    const int tid = threadIdx.x;
    const int mg = tid >> 4;      // 0..15 : rows i = i0 + {0,64} + mg*4 + ii
    const int ng = tid & 15;      // 0..15 : cols n = n0 + {0,64} + ng*4 + j
    const int mg4 = mg << 2;
    const int ng4 = ng << 2;

    float acc[8][8];              // [rowhalf*4+ii][colhalf*4+j]
    #pragma unroll
    for (int i=0;i<8;i++)
        #pragma unroll
        for (int j=0;j<8;j++) acc[i][j]=0.f;

    for (int kc = 0; kc < DM_; kc += 32) {
        __syncthreads();
        #pragma unroll
        for (int w = 0; w < 4; w++) {
            int idx = tid + w*256;            // 0..1023
            int m = idx >> 3, k4 = idx & 7;
            float4 v = *(const float4*)&MHA[(long)(i0 + m)*DM_ + kc + k4*4];
            int col = (((m >> 2) ^ k4) << 2) + (m & 3);
            sA[(k4*4+0)*132 + col] = v.x;
            sA[(k4*4+1)*132 + col] = v.y;
            sA[(k4*4+2)*132 + col] = v.z;
            sA[(k4*4+3)*132 + col] = v.w;
        }
        #pragma unroll
        for (int w = 0; w < 4; w++) {
            int idx = tid + w*256;
            int n = idx >> 3, k4 = idx & 7;
            float4 v = *(const float4*)&Wout[(long)(n0 + n)*DM_ + kc + k4*4];
            int col = (((n >> 2) ^ k4) << 2) + (n & 3);
            sW[(k4*4+0)*132 + col] = v.x;
            sW[(k4*4+1)*132 + col] = v.y;
            sW[(k4*4+2)*132 + col] = v.z;
            sW[(k4*4+3)*132 + col] = v.w;
        }
        __syncthreads();
        #pragma unroll
        for (int kk = 0; kk < 32; kk++) {
            const int c4 = (kk >> 2) << 2;
            const int sm = mg4 ^ c4;
            const int sn = ng4 ^ c4;
            const float4 a0 = *(const float4*)&sA[kk*132 + sm];        // rows mg*4..
            const float4 a1 = *(const float4*)&sA[kk*132 + 64 + sm];   // rows 64+mg*4..
            const float4 b0 = *(const float4*)&sW[kk*132 + sn];        // cols ng*4..
            const float4 b1 = *(const float4*)&sW[kk*132 + 64 + sn];   // cols 64+ng*4..
            const float a[8] = {a0.x,a0.y,a0.z,a0.w,a1.x,a1.y,a1.z,a1.w};
            const float b[8] = {b0.x,b0.y,b0.z,b0.w,b1.x,b1.y,b1.z,b1.w};
            #pragma unroll
            for (int i=0;i<8;i++)
                #pragma unroll
                for (int j=0;j<8;j++)
                    acc[i][j] = fmaf(a[i], b[j], acc[i][j]);
        }
    }

    const float4 bv0 = *(const float4*)&bout[n0 + ng4];
    const float4 bv1 = *(const float4*)&bout[n0 + 64 + ng4];
    const float bb[8] = {bv0.x,bv0.y,bv0.z,bv0.w,bv1.x,bv1.y,bv1.z,bv1.w};
    #pragma unroll
    for (int ih = 0; ih < 2; ih++)
        #pragma unroll
        for (int ii = 0; ii < 4; ii++) {
            const int ai = ih*4 + ii;
            const long row = (long)(i0 + ih*64 + mg4 + ii)*DM_ + n0;
            float4 o0, o1;
            o0.x = acc[ai][0]+bb[0]; o0.y = acc[ai][1]+bb[1];
            o0.z = acc[ai][2]+bb[2]; o0.w = acc[ai][3]+bb[3];
            o1.x = acc[ai][4]+bb[4]; o1.y = acc[ai][5]+bb[5];
            o1.z = acc[ai][6]+bb[6]; o1.w = acc[ai][7]+bb[7];
            *(float4*)&Yout[row + ng4]      = o0;
            *(float4*)&Yout[row + 64 + ng4] = o1;
        }
}

// ---------------------------------------------------------------------------
extern "C" void kernel_launch(void* const* d_in, const int* in_sizes, int n_in,
                              void* d_out, int out_size, void* d_ws, size_t ws_size,
                              hipStream_t stream)
{
    const float* query = (const float*)d_in[0];
    const float* key   = (const float*)d_in[1];
    const float* value = (const float*)d_in[2];
    const float* Wq    = (const float*)d_in[3];
    const float* bq    = (const float*)d_in[4];
    const float* Wk    = (const float*)d_in[5];
    const float* bk    = (const float*)d_in[6];
    const float* Wv    = (const float*)d_in[7];
    const float* bv    = (const float*)d_in[8];
    const float* E_w   = (const float*)d_in[9];
    const float* E_b   = (const float*)d_in[10];
    const float* F_w   = (const float*)d_in[11];
    const float* F_b   = (const float*)d_in[12];
    const float* out_w = (const float*)d_in[13];
    const float* out_b = (const float*)d_in[14];

    float* ws   = (float*)d_ws;
    float* Qb   = ws;                    // [B,H,S,DH]
    float* Kb   = ws + (size_t)NBHSD;    // [B,H,S,DH]
    float* Vb   = ws + (size_t)2*NBHSD;  // [B,H,S,DH]
    float* KEt  = ws + (size_t)3*NBHSD;  // [B,H,T,DH]
    float* VF   = ws + (size_t)4*NBHSD;  // [B,H,T,DH]
    float* MHA  = Qb;                    // reuse Q slot after attn kernel: [B,S,DM]

    float* mha_out = (float*)d_out;                 // [B,S,DM]
    float* attn    = (float*)d_out + OFF_ATTN;      // [B,H,S,T]

    // 1) Q/K/V projections
    qkv_proj_kernel<<<dim3(S_/64, H_, 3*B_), 256, 0, stream>>>(
        query, key, value, Wq, bq, Wk, bk, Wv, bv, Qb, Kb, Vb);

    // 2) KEt[bh][t][d] = sum_s E_w[t,s]*K[bh,s,d] + E_b[t]
    gemm128x64_kernel<<<dim3(T_/128, B_*H_), 256, 0, stream>>>(
        E_w, 0, S_, Kb, (long)S_*DH_, E_b,
        KEt, (long)H_*T_*DH_, (long)T_*DH_, DH_);
    //    VF[bh][t][d] = sum_s F_w[t,s]*V[bh,s,d] + F_b[t]
    gemm128x64_kernel<<<dim3(T_/128, B_*H_), 256, 0, stream>>>(
        F_w, 0, S_, Vb, (long)S_*DH_, F_b,
        VF, (long)H_*T_*DH_, (long)T_*DH_, DH_);

    // 3) attn = softmax(Q . KEt^T / 8) -> d_out attn region
    attn_softmax_kernel<<<dim3(S_/32, B_*H_), 256, 0, stream>>>(Qb, KEt, attn);

    // 4) head_out -> MHA[b][s][h*64+d] = sum_t attn[bh,s,t]*VF[bh,t,d]
    gemm128x64_kernel<<<dim3(S_/128, B_*H_), 256, 0, stream>>>(
        attn, (long)S_*T_, T_, VF, (long)T_*DH_, nullptr,
        MHA, (long)S_*DM_, (long)DH_, DM_);

    // 5) output projection
    outproj_kernel<<<dim3(B_*S_/128, DM_/128), 256, 0, stream>>>(
        MHA, out_w, out_b, mha_out);
}

// Round 3
// 1818.458 us; speedup vs baseline: 1.8539x; 1.1624x over previous
//
#include <hip/hip_runtime.h>
#include <math.h>

#define B_  32
#define S_  512
#define H_  16
#define DH_ 64
#define DM_ 1024
#define T_  512

// sizes
#define NBHSD (B_*H_*S_*DH_)          // 16,777,216 elements (also B*S*DM)
#define OFF_ATTN ((size_t)B_*S_*DM_)  // mha_out element count in d_out

typedef __attribute__((ext_vector_type(8))) short     bf16x8;
typedef __attribute__((ext_vector_type(4))) float     f32x4;
typedef __attribute__((ext_vector_type(8))) unsigned short u16x8;

// fp32 -> bf16 (RNE) bit helpers
__device__ __forceinline__ unsigned short f2bf(float x) {
    unsigned int u = __float_as_uint(x);
    u = (u + 0x7FFFu + ((u >> 16) & 1u)) >> 16;
    return (unsigned short)u;
}
__device__ __forceinline__ float bf2f(unsigned short h) {
    return __uint_as_float(((unsigned int)h) << 16);
}

// ---------------------------------------------------------------------------
// Kernel 1: per-head Q/K/V projection.  (unchanged)
// ---------------------------------------------------------------------------
__global__ __launch_bounds__(256)
void qkv_proj_kernel(const float* __restrict__ q_in, const float* __restrict__ k_in,
                     const float* __restrict__ v_in,
                     const float* __restrict__ Wq, const float* __restrict__ bq,
                     const float* __restrict__ Wk, const float* __restrict__ bk,
                     const float* __restrict__ Wv, const float* __restrict__ bv,
                     float* __restrict__ Qo, float* __restrict__ Ko, float* __restrict__ Vo)
{
    const int stile = blockIdx.x;
    const int h     = blockIdx.y;
    const int which = blockIdx.z / B_;
    const int b     = blockIdx.z % B_;

    const float* xin; const float* W; const float* bias; float* out;
    if (which == 0)      { xin = q_in; W = Wq; bias = bq; out = Qo; }
    else if (which == 1) { xin = k_in; W = Wk; bias = bk; out = Ko; }
    else                 { xin = v_in; W = Wv; bias = bv; out = Vo; }

    __shared__ float sA[32*68];
    __shared__ float sW[32*68];

    const int tid = threadIdx.x;
    const int dg = tid & 15;
    const int tg = tid >> 4;
    const int s0 = stile * 64;

    float acc[4][4];
    #pragma unroll
    for (int i=0;i<4;i++)
        #pragma unroll
        for (int j=0;j<4;j++) acc[i][j]=0.f;

    for (int dc = 0; dc < 64; dc += 32) {
        __syncthreads();
        for (int idx = tid; idx < 64*32; idx += 256) {
            int s = idx >> 5, d = idx & 31;
            sA[d*68 + s] = xin[((size_t)b*S_ + s0 + s)*DH_ + dc + d];
        }
        for (int idx = tid; idx < 64*32; idx += 256) {
            int e = idx >> 5, d = idx & 31;
            sW[d*68 + e] = W[(size_t)h*DH_*DH_ + (size_t)e*DH_ + dc + d];
        }
        __syncthreads();
        #pragma unroll
        for (int kk = 0; kk < 32; kk++) {
            const float4 a4 = *(const float4*)&sA[kk*68 + tg*4];
            const float4 w4 = *(const float4*)&sW[kk*68 + dg*4];
            const float a[4] = {a4.x,a4.y,a4.z,a4.w};
            const float w[4] = {w4.x,w4.y,w4.z,w4.w};
            #pragma unroll
            for (int i=0;i<4;i++)
                #pragma unroll
                for (int j=0;j<4;j++)
                    acc[i][j] = fmaf(a[i], w[j], acc[i][j]);
        }
    }

    const float4 bv4 = *(const float4*)&bias[h*DH_ + dg*4];
    const float bb[4] = {bv4.x,bv4.y,bv4.z,bv4.w};
    #pragma unroll
    for (int i=0;i<4;i++) {
        int s = s0 + tg*4 + i;
        float4 o;
        o.x = acc[i][0]+bb[0]; o.y = acc[i][1]+bb[1];
        o.z = acc[i][2]+bb[2]; o.w = acc[i][3]+bb[3];
        *(float4*)&out[(((size_t)b*H_ + h)*S_ + s)*DH_ + dg*4] = o;
    }
}

// ---------------------------------------------------------------------------
// Kernel 2 (E/F): Y[bh][m][d] = sum_k A[m][k] * X[bh][k][d]  (+bias[m])
// (unchanged from round 2)
// ---------------------------------------------------------------------------
__global__ __launch_bounds__(256)
void gemm128x64_kernel(const float* __restrict__ A, long a_bh_stride, int K,
                       const float* __restrict__ X, long x_bh_stride,
                       const float* __restrict__ bias,
                       float* __restrict__ Y, long y_b_stride, long y_h_stride,
                       int y_row_stride)
{
    const int mtile = blockIdx.x;
    const int bh    = blockIdx.y;

    const float* Ab = A + (long)bh * a_bh_stride + (long)mtile*128*K;
    const float* Xb = X + (long)bh * x_bh_stride;

    __shared__ float sA[32*132];
    __shared__ float sX[32*72];

    const int tid = threadIdx.x;
    const int mg = tid >> 3;
    const int dg = tid & 7;
    const int mg4 = mg << 2;
    const int dg4 = dg << 2;

    float acc[4][8];
    #pragma unroll
    for (int i=0;i<4;i++)
        #pragma unroll
        for (int j=0;j<8;j++) acc[i][j]=0.f;

    for (int kc = 0; kc < K; kc += 32) {
        __syncthreads();
        #pragma unroll
        for (int w = 0; w < 4; w++) {
            int idx = tid + w*256;
            int m = idx >> 3, k4 = idx & 7;
            float4 v = *(const float4*)&Ab[(long)m*K + kc + k4*4];
            int col = (((m >> 2) ^ k4) << 2) + (m & 3);
            sA[(k4*4+0)*132 + col] = v.x;
            sA[(k4*4+1)*132 + col] = v.y;
            sA[(k4*4+2)*132 + col] = v.z;
            sA[(k4*4+3)*132 + col] = v.w;
        }
        #pragma unroll
        for (int w = 0; w < 2; w++) {
            int idx = tid + w*256;
            int k = idx >> 4, d4 = idx & 15;
            *(float4*)&sX[k*72 + d4*4] = *(const float4*)&Xb[(long)(kc+k)*64 + d4*4];
        }
        __syncthreads();
        #pragma unroll
        for (int kk = 0; kk < 32; kk++) {
            const int sm = mg4 ^ ((kk >> 2) << 2);
            const float4 a4 = *(const float4*)&sA[kk*132 + sm];
            const float4 x0 = *(const float4*)&sX[kk*72 + dg4];
            const float4 x1 = *(const float4*)&sX[kk*72 + 32 + dg4];
            const float a[4] = {a4.x,a4.y,a4.z,a4.w};
            const float x[8] = {x0.x,x0.y,x0.z,x0.w,x1.x,x1.y,x1.z,x1.w};
            #pragma unroll
            for (int i=0;i<4;i++)
                #pragma unroll
                for (int j=0;j<8;j++)
                    acc[i][j] = fmaf(a[i], x[j], acc[i][j]);
        }
    }

    const long ybase = (long)(bh >> 4)*y_b_stride + (long)(bh & 15)*y_h_stride
                     + (long)mtile*128*y_row_stride;
    #pragma unroll
    for (int i=0;i<4;i++) {
        int m = mg4 + i;
        float bval = bias ? bias[mtile*128 + m] : 0.f;
        float4 o0, o1;
        o0.x = acc[i][0]+bval; o0.y = acc[i][1]+bval;
        o0.z = acc[i][2]+bval; o0.w = acc[i][3]+bval;
        o1.x = acc[i][4]+bval; o1.y = acc[i][5]+bval;
        o1.z = acc[i][6]+bval; o1.w = acc[i][7]+bval;
        *(float4*)&Y[ybase + (long)m*y_row_stride + dg4]      = o0;
        *(float4*)&Y[ybase + (long)m*y_row_stride + 32 + dg4] = o1;
    }
}

// ---------------------------------------------------------------------------
// Kernel 3: scores + softmax (unchanged from round 2)
// ---------------------------------------------------------------------------
__global__ __launch_bounds__(256)
void attn_softmax_kernel(const float* __restrict__ Q, const float* __restrict__ KEt,
                         float* __restrict__ attnOut)
{
    const int stile = blockIdx.x;
    const int bh    = blockIdx.y;

    __shared__ float sQt[64*36];
    __shared__ float sKt[64*132];

    const int tid = threadIdx.x;
    const int sq  = tid >> 5;
    const int tq  = tid & 31;
    const int tq4 = tq << 2;
    const int s0  = stile * 32;

    #pragma unroll
    for (int w = 0; w < 2; w++) {
        int idx = tid + w*256;
        int s = idx >> 4, d4 = idx & 15;
        float4 v = *(const float4*)&Q[((size_t)bh*S_ + s0 + s)*DH_ + d4*4];
        sQt[(d4*4+0)*36 + s] = v.x * 0.125f;
        sQt[(d4*4+1)*36 + s] = v.y * 0.125f;
        sQt[(d4*4+2)*36 + s] = v.z * 0.125f;
        sQt[(d4*4+3)*36 + s] = v.w * 0.125f;
    }

    float p[4][4][4];

    #pragma unroll
    for (int c = 0; c < 4; c++) {
        __syncthreads();
        #pragma unroll
        for (int w = 0; w < 8; w++) {
            int idx = tid + w*256;
            int t = idx >> 4, d4 = idx & 15;
            float4 v = *(const float4*)&KEt[((size_t)bh*T_ + c*128 + t)*DH_ + d4*4];
            int col = (((t >> 2) ^ d4) << 2) + (t & 3);
            sKt[(d4*4+0)*132 + col] = v.x;
            sKt[(d4*4+1)*132 + col] = v.y;
            sKt[(d4*4+2)*132 + col] = v.z;
            sKt[(d4*4+3)*132 + col] = v.w;
        }
        __syncthreads();

        #pragma unroll
        for (int i=0;i<4;i++)
            #pragma unroll
            for (int j=0;j<4;j++) p[c][i][j] = 0.f;

        #pragma unroll
        for (int kk = 0; kk < 64; kk++) {
            const float4 q4 = *(const float4*)&sQt[kk*36 + sq*4];
            const int st = tq4 ^ ((kk >> 2) << 2);
            const float4 k4 = *(const float4*)&sKt[kk*132 + st];
            const float q[4] = {q4.x,q4.y,q4.z,q4.w};
            const float k[4] = {k4.x,k4.y,k4.z,k4.w};
            #pragma unroll
            for (int i=0;i<4;i++)
                #pragma unroll
                for (int j=0;j<4;j++)
                    p[c][i][j] = fmaf(q[i], k[j], p[c][i][j]);
        }
    }

    #pragma unroll
    for (int i = 0; i < 4; i++) {
        float m = -INFINITY;
        #pragma unroll
        for (int c = 0; c < 4; c++)
            #pragma unroll
            for (int j = 0; j < 4; j++) m = fmaxf(m, p[c][i][j]);
        #pragma unroll
        for (int off = 16; off >= 1; off >>= 1) m = fmaxf(m, __shfl_xor(m, off));

        float sum = 0.f;
        #pragma unroll
        for (int c = 0; c < 4; c++)
            #pragma unroll
            for (int j = 0; j < 4; j++) {
                p[c][i][j] = __expf(p[c][i][j] - m);
                sum += p[c][i][j];
            }
        #pragma unroll
        for (int off = 16; off >= 1; off >>= 1) sum += __shfl_xor(sum, off);
        const float inv = 1.f / sum;

        const size_t rowbase = ((size_t)bh*S_ + s0 + sq*4 + i)*T_;
        #pragma unroll
        for (int c = 0; c < 4; c++) {
            float4 o;
            o.x = p[c][i][0]*inv; o.y = p[c][i][1]*inv;
            o.z = p[c][i][2]*inv; o.w = p[c][i][3]*inv;
            *(float4*)&attnOut[rowbase + c*128 + tq4] = o;
        }
    }
}

// ---------------------------------------------------------------------------
// Kernel 4: PV with bf16 hi/lo output.
//   MHA[b][s][h*64+d] = sum_t attn[bh,s,t]*VF[bh,t,d]  -> (Yhi, Ylo) ushort
// grid (S/128, B*H), block 256. Same structure as gemm128x64.
// ---------------------------------------------------------------------------
__global__ __launch_bounds__(256)
void pv_bf16out_kernel(const float* __restrict__ A, const float* __restrict__ X,
                       ushort* __restrict__ Yhi, ushort* __restrict__ Ylo)
{
    const int mtile = blockIdx.x;
    const int bh    = blockIdx.y;

    const float* Ab = A + (size_t)bh*S_*T_ + (size_t)mtile*128*T_;
    const float* Xb = X + (size_t)bh*T_*DH_;

    __shared__ float sA[32*132];
    __shared__ float sX[32*72];

    const int tid = threadIdx.x;
    const int mg = tid >> 3;
    const int dg = tid & 7;
    const int mg4 = mg << 2;
    const int dg4 = dg << 2;

    float acc[4][8];
    #pragma unroll
    for (int i=0;i<4;i++)
        #pragma unroll
        for (int j=0;j<8;j++) acc[i][j]=0.f;

    for (int kc = 0; kc < T_; kc += 32) {
        __syncthreads();
        #pragma unroll
        for (int w = 0; w < 4; w++) {
            int idx = tid + w*256;
            int m = idx >> 3, k4 = idx & 7;
            float4 v = *(const float4*)&Ab[(long)m*T_ + kc + k4*4];
            int col = (((m >> 2) ^ k4) << 2) + (m & 3);
            sA[(k4*4+0)*132 + col] = v.x;
            sA[(k4*4+1)*132 + col] = v.y;
            sA[(k4*4+2)*132 + col] = v.z;
            sA[(k4*4+3)*132 + col] = v.w;
        }
        #pragma unroll
        for (int w = 0; w < 2; w++) {
            int idx = tid + w*256;
            int k = idx >> 4, d4 = idx & 15;
            *(float4*)&sX[k*72 + d4*4] = *(const float4*)&Xb[(long)(kc+k)*64 + d4*4];
        }
        __syncthreads();
        #pragma unroll
        for (int kk = 0; kk < 32; kk++) {
            const int sm = mg4 ^ ((kk >> 2) << 2);
            const float4 a4 = *(const float4*)&sA[kk*132 + sm];
            const float4 x0 = *(const float4*)&sX[kk*72 + dg4];
            const float4 x1 = *(const float4*)&sX[kk*72 + 32 + dg4];
            const float a[4] = {a4.x,a4.y,a4.z,a4.w};
            const float x[8] = {x0.x,x0.y,x0.z,x0.w,x1.x,x1.y,x1.z,x1.w};
            #pragma unroll
            for (int i=0;i<4;i++)
                #pragma unroll
                for (int j=0;j<8;j++)
                    acc[i][j] = fmaf(a[i], x[j], acc[i][j]);
        }
    }

    // ybase in elements: MHA[b][s][h*64+d]
    const size_t ybase = (size_t)(bh >> 4)*S_*DM_ + (size_t)(bh & 15)*DH_
                       + (size_t)mtile*128*DM_;
    #pragma unroll
    for (int i=0;i<4;i++) {
        const int m = mg4 + i;
        const size_t rb = ybase + (size_t)m*DM_;
        ushort4 h0, l0, h1, l1;
        h0.x = f2bf(acc[i][0]); l0.x = f2bf(acc[i][0] - bf2f(h0.x));
        h0.y = f2bf(acc[i][1]); l0.y = f2bf(acc[i][1] - bf2f(h0.y));
        h0.z = f2bf(acc[i][2]); l0.z = f2bf(acc[i][2] - bf2f(h0.z));
        h0.w = f2bf(acc[i][3]); l0.w = f2bf(acc[i][3] - bf2f(h0.w));
        h1.x = f2bf(acc[i][4]); l1.x = f2bf(acc[i][4] - bf2f(h1.x));
        h1.y = f2bf(acc[i][5]); l1.y = f2bf(acc[i][5] - bf2f(h1.y));
        h1.z = f2bf(acc[i][6]); l1.z = f2bf(acc[i][6] - bf2f(h1.z));
        h1.w = f2bf(acc[i][7]); l1.w = f2bf(acc[i][7] - bf2f(h1.w));
        *(ushort4*)&Yhi[rb + dg4]      = h0;
        *(ushort4*)&Ylo[rb + dg4]      = l0;
        *(ushort4*)&Yhi[rb + 32 + dg4] = h1;
        *(ushort4*)&Ylo[rb + 32 + dg4] = l1;
    }
}

// ---------------------------------------------------------------------------
// Kernel 4b: Wout fp32 -> bf16 hi/lo split. 1M elements.
// ---------------------------------------------------------------------------
__global__ __launch_bounds__(256)
void wconv_kernel(const float* __restrict__ W, ushort* __restrict__ Whi,
                  ushort* __restrict__ Wlo)
{
    const size_t i = ((size_t)blockIdx.x*256 + threadIdx.x)*4;
    float4 v = *(const float4*)&W[i];
    ushort4 h, l;
    h.x = f2bf(v.x); l.x = f2bf(v.x - bf2f(h.x));
    h.y = f2bf(v.y); l.y = f2bf(v.y - bf2f(h.y));
    h.z = f2bf(v.z); l.z = f2bf(v.z - bf2f(h.z));
    h.w = f2bf(v.w); l.w = f2bf(v.w - bf2f(h.w));
    *(ushort4*)&Whi[i] = h;
    *(ushort4*)&Wlo[i] = l;
}

// ---------------------------------------------------------------------------
// Kernel 5: out projection via split-bf16 MFMA (3x mfma_f32_16x16x32_bf16).
//   C[i][n] = sum_k MHA[i][k]*Wout[n][k] + bout[n], both operands hi/lo bf16.
//   Block 128x128, 4 waves (2x2), wave tile 64x64 = 4x4 frags of 16x16.
//   LDS [row][k] stride 40 ushort (80B) -> conflict-free b128 frag reads.
// grid (B*S/128, DM/128), block 256.
// ---------------------------------------------------------------------------
__global__ __launch_bounds__(256)
void outproj_mfma_kernel(const ushort* __restrict__ Ahi, const ushort* __restrict__ Alo,
                         const ushort* __restrict__ Bhi, const ushort* __restrict__ Blo,
                         const float* __restrict__ bout, float* __restrict__ Yout)
{
    const int i0 = blockIdx.x * 128;
    const int n0 = blockIdx.y * 128;

    __shared__ __align__(16) ushort sAh[128*40];
    __shared__ __align__(16) ushort sAl[128*40];
    __shared__ __align__(16) ushort sBh[128*40];
    __shared__ __align__(16) ushort sBl[128*40];

    const int tid  = threadIdx.x;
    const int lane = tid & 63;
    const int wave = tid >> 6;          // 0..3
    const int wm   = wave >> 1;         // wave row  (0,1)
    const int wn   = wave & 1;          // wave col  (0,1)
    const int l15  = lane & 15;         // frag row/col within 16
    const int l4   = lane >> 4;         // k-slice 0..3 (8 bf16 each)

    const int srow = tid >> 2;          // staging row 0..63 (x2 passes)
    const int koff = (tid & 3) * 8;     // staging k-octet

    f32x4 acc[4][4];
    #pragma unroll
    for (int a=0;a<4;a++)
        #pragma unroll
        for (int b=0;b<4;b++)
            acc[a][b] = (f32x4){0.f,0.f,0.f,0.f};

    for (int kc = 0; kc < DM_; kc += 32) {
        __syncthreads();
        #pragma unroll
        for (int p = 0; p < 2; p++) {
            const int r = p*64 + srow;
            const size_t gi = (size_t)(i0 + r)*DM_ + kc + koff;
            const size_t gn = (size_t)(n0 + r)*DM_ + kc + koff;
            *(u16x8*)&sAh[r*40 + koff] = *(const u16x8*)&Ahi[gi];
            *(u16x8*)&sAl[r*40 + koff] = *(const u16x8*)&Alo[gi];
            *(u16x8*)&sBh[r*40 + koff] = *(const u16x8*)&Bhi[gn];
            *(u16x8*)&sBl[r*40 + koff] = *(const u16x8*)&Blo[gn];
        }
        __syncthreads();

        bf16x8 ah[4], al[4], bh[4], bl[4];
        #pragma unroll
        for (int q = 0; q < 4; q++) {
            ah[q] = *(const bf16x8*)&sAh[(wm*64 + q*16 + l15)*40 + l4*8];
            al[q] = *(const bf16x8*)&sAl[(wm*64 + q*16 + l15)*40 + l4*8];
            bh[q] = *(const bf16x8*)&sBh[(wn*64 + q*16 + l15)*40 + l4*8];
            bl[q] = *(const bf16x8*)&sBl[(wn*64 + q*16 + l15)*40 + l4*8];
        }
        // pass 1: hi*hi
        #pragma unroll
        for (int mb=0; mb<4; mb++)
            #pragma unroll
            for (int nb=0; nb<4; nb++)
                acc[mb][nb] = __builtin_amdgcn_mfma_f32_16x16x32_bf16(
                                  ah[mb], bh[nb], acc[mb][nb], 0, 0, 0);
        // pass 2: hi*lo
        #pragma unroll
        for (int mb=0; mb<4; mb++)
            #pragma unroll
            for (int nb=0; nb<4; nb++)
                acc[mb][nb] = __builtin_amdgcn_mfma_f32_16x16x32_bf16(
                                  ah[mb], bl[nb], acc[mb][nb], 0, 0, 0);
        // pass 3: lo*hi
        #pragma unroll
        for (int mb=0; mb<4; mb++)
            #pragma unroll
            for (int nb=0; nb<4; nb++)
                acc[mb][nb] = __builtin_amdgcn_mfma_f32_16x16x32_bf16(
                                  al[mb], bh[nb], acc[mb][nb], 0, 0, 0);
    }

    // epilogue: C/D layout col=lane&15, row=(lane>>4)*4+reg  (guide-verified)
    #pragma unroll
    for (int nb = 0; nb < 4; nb++) {
        const int n = n0 + wn*64 + nb*16 + l15;
        const float bias = bout[n];
        #pragma unroll
        for (int mb = 0; mb < 4; mb++) {
            #pragma unroll
            for (int r = 0; r < 4; r++) {
                const int row = i0 + wm*64 + mb*16 + l4*4 + r;
                Yout[(size_t)row*DM_ + n] = acc[mb][nb][r] + bias;
            }
        }
    }
}

// ---------------------------------------------------------------------------
extern "C" void kernel_launch(void* const* d_in, const int* in_sizes, int n_in,
                              void* d_out, int out_size, void* d_ws, size_t ws_size,
                              hipStream_t stream)
{
    const float* query = (const float*)d_in[0];
    const float* key   = (const float*)d_in[1];
    const float* value = (const float*)d_in[2];
    const float* Wq    = (const float*)d_in[3];
    const float* bq    = (const float*)d_in[4];
    const float* Wk    = (const float*)d_in[5];
    const float* bk    = (const float*)d_in[6];
    const float* Wv    = (const float*)d_in[7];
    const float* bv    = (const float*)d_in[8];
    const float* E_w   = (const float*)d_in[9];
    const float* E_b   = (const float*)d_in[10];
    const float* F_w   = (const float*)d_in[11];
    const float* F_b   = (const float*)d_in[12];
    const float* out_w = (const float*)d_in[13];
    const float* out_b = (const float*)d_in[14];

    float* ws   = (float*)d_ws;
    float* Qb   = ws;                    // [B,H,S,DH]
    float* Kb   = ws + (size_t)NBHSD;    // [B,H,S,DH]  (free after E-proj)
    float* Vb   = ws + (size_t)2*NBHSD;  // [B,H,S,DH]  (free after F-proj)
    float* KEt  = ws + (size_t)3*NBHSD;  // [B,H,T,DH]
    float* VF   = ws + (size_t)4*NBHSD;  // [B,H,T,DH]

    // bf16 hi/lo buffers carved from freed fp32 slots
    ushort* MHAhi = (ushort*)Qb;                  // 16.7M ushort (Qb free after attn)
    ushort* MHAlo = MHAhi + (size_t)NBHSD;
    ushort* Whi   = (ushort*)Kb;                  // 1M ushort (Kb free after E-proj)
    ushort* Wlo   = Whi + (size_t)DM_*DM_;

    float* mha_out = (float*)d_out;                 // [B,S,DM]
    float* attn    = (float*)d_out + OFF_ATTN;      // [B,H,S,T]

    // 1) Q/K/V projections
    qkv_proj_kernel<<<dim3(S_/64, H_, 3*B_), 256, 0, stream>>>(
        query, key, value, Wq, bq, Wk, bk, Wv, bv, Qb, Kb, Vb);

    // 2) KEt[bh][t][d] = sum_s E_w[t,s]*K[bh,s,d] + E_b[t]
    gemm128x64_kernel<<<dim3(T_/128, B_*H_), 256, 0, stream>>>(
        E_w, 0, S_, Kb, (long)S_*DH_, E_b,
        KEt, (long)H_*T_*DH_, (long)T_*DH_, DH_);
    //    VF[bh][t][d] = sum_s F_w[t,s]*V[bh,s,d] + F_b[t]
    gemm128x64_kernel<<<dim3(T_/128, B_*H_), 256, 0, stream>>>(
        F_w, 0, S_, Vb, (long)S_*DH_, F_b,
        VF, (long)H_*T_*DH_, (long)T_*DH_, DH_);

    // 2b) Wout -> bf16 hi/lo (into freed Kb space)
    wconv_kernel<<<dim3(DM_*DM_/1024), 256, 0, stream>>>(out_w, Whi, Wlo);

    // 3) attn = softmax(Q . KEt^T / 8) -> d_out attn region
    attn_softmax_kernel<<<dim3(S_/32, B_*H_), 256, 0, stream>>>(Qb, KEt, attn);

    // 4) head_out -> MHA as bf16 hi/lo (into freed Qb space)
    pv_bf16out_kernel<<<dim3(S_/128, B_*H_), 256, 0, stream>>>(
        attn, VF, MHAhi, MHAlo);

    // 5) output projection via split-bf16 MFMA
    outproj_mfma_kernel<<<dim3(B_*S_/128, DM_/128), 256, 0, stream>>>(
        MHAhi, MHAlo, Whi, Wlo, out_b, mha_out);
}